// Round 3
// baseline (320.942 us; speedup 1.0000x reference)
//
#include <hip/hip_runtime.h>
#include <hip/hip_bf16.h>
#include <math.h>

#define EPSF 1e-8f
#define LN_EPSF 1e-5f
#define SCALE_QK 0.04419417382415922f   // 512^-0.5

typedef unsigned short ushort_t;
typedef __bf16 bhalf;
typedef bhalf bhalf8 __attribute__((ext_vector_type(8)));
typedef float f32x4 __attribute__((ext_vector_type(4)));

__device__ __forceinline__ float b2f(ushort_t u) {
    return __uint_as_float((unsigned)u << 16);
}
// fp32 -> bf16 RNE (matches numpy/jax rounding)
__device__ __forceinline__ ushort_t f2b(float f) {
    unsigned x = __float_as_uint(f);
    return (ushort_t)((x + 0x7fffu + ((x >> 16) & 1u)) >> 16);
}
// pack two fp32 -> one dword of two bf16 (RNE), lo in bits[15:0]
__device__ __forceinline__ unsigned pk2(float lo, float hi) {
    return (unsigned)f2b(lo) | ((unsigned)f2b(hi) << 16);
}
// async 16B global -> LDS (lands at wave-uniform base + lane*16)
__device__ __forceinline__ void gload16(const ushort_t* g, ushort_t* l) {
    __builtin_amdgcn_global_load_lds(
        (const __attribute__((address_space(1))) unsigned int*)g,
        (__attribute__((address_space(3))) unsigned int*)l, 16, 0, 0);
}

// ---------------------------------------------------------------------------
// Bias helper vectors: wqbk = Wq@bk, wkbq = Wk@bq, cc = bq.bk.
// grid (32,3), block 256.  (All zero for this problem's inputs, but exact.)
// ---------------------------------------------------------------------------
__global__ __launch_bounds__(256) void mv_bias_kernel(
    const float* __restrict__ Wq, const float* __restrict__ Wk,
    const float* __restrict__ bq, const float* __restrict__ bk,
    float* __restrict__ wqbk, float* __restrict__ wkbq, float* __restrict__ cc)
{
    __shared__ float ls[4];
    const int y = blockIdx.y;
    const int t = threadIdx.x;
    if (y == 2) {
        if (blockIdx.x != 0) return;
        float s = bq[t] * bk[t] + bq[t + 256] * bk[t + 256];
#pragma unroll
        for (int off = 32; off > 0; off >>= 1) s += __shfl_down(s, off, 64);
        int lane = t & 63, w = t >> 6;
        if (lane == 0) ls[w] = s;
        __syncthreads();
        if (t == 0) cc[0] = ls[0] + ls[1] + ls[2] + ls[3];
        return;
    }
    const float* W = y ? Wk : Wq;
    const float* v = y ? bq : bk;
    float* o = y ? wkbq : wqbk;
    const int row = blockIdx.x * 16 + (t >> 4);
    const int l = t & 15;
    const float* wr = W + (size_t)row * 512 + l * 32;
    const float* vr = v + l * 32;
    float s = 0.f;
#pragma unroll
    for (int c = 0; c < 32; ++c) s += wr[c] * vr[c];
#pragma unroll
    for (int off = 8; off > 0; off >>= 1) s += __shfl_down(s, off, 16);
    if (l == 0) o[row] = s;
}

// ---------------------------------------------------------------------------
// LayerNorm: stats + apply + bf16 store + dot with bias helper (t1/t2).
// grid (16384, 2), block 256.  Row = 512 floats, float2 per thread.
// ---------------------------------------------------------------------------
__global__ __launch_bounds__(256) void ln_apply_kernel(
    const float* __restrict__ X1, const float* __restrict__ X2,
    const float* __restrict__ g1, const float* __restrict__ b1,
    const float* __restrict__ g2, const float* __restrict__ b2,
    const float* __restrict__ wb1, const float* __restrict__ wb2,
    ushort_t* __restrict__ O1, ushort_t* __restrict__ O2,
    float* __restrict__ T1, float* __restrict__ T2)
{
    const bool sec = blockIdx.y != 0;
    const float* X = sec ? X2 : X1;
    const float* g = sec ? g2 : g1;
    const float* b = sec ? b2 : b1;
    const float* wb = sec ? wb2 : wb1;
    ushort_t* O = sec ? O2 : O1;
    float* T = sec ? T2 : T1;
    const size_t base = (size_t)blockIdx.x * 512;
    const int t = threadIdx.x;
    float2 x = ((const float2*)(X + base))[t];
    float s = x.x + x.y;
    float q = fmaf(x.x, x.x, x.y * x.y);
#pragma unroll
    for (int off = 32; off > 0; off >>= 1) {
        s += __shfl_down(s, off, 64);
        q += __shfl_down(q, off, 64);
    }
    __shared__ float ls[4], lq[4], mv[2], ld[4];
    int lane = t & 63, w = t >> 6;
    if (lane == 0) { ls[w] = s; lq[w] = q; }
    __syncthreads();
    if (t == 0) {
        float st = ls[0] + ls[1] + ls[2] + ls[3];
        float qt = lq[0] + lq[1] + lq[2] + lq[3];
        float mu = st * (1.0f / 512.0f);
        float var = qt * (1.0f / 512.0f) - mu * mu;
        mv[0] = mu;
        mv[1] = rsqrtf(var + LN_EPSF);
    }
    __syncthreads();
    const float mu = mv[0], rstd = mv[1];
    float2 gg = ((const float2*)g)[t];
    float2 bb = ((const float2*)b)[t];
    float2 ww = ((const float2*)wb)[t];
    float o0 = (x.x - mu) * rstd * gg.x + bb.x;
    float o1 = (x.y - mu) * rstd * gg.y + bb.y;
    ((unsigned*)O)[blockIdx.x * 256 + t] = pk2(o0, o1);
    float d = o0 * ww.x + o1 * ww.y;
#pragma unroll
    for (int off = 32; off > 0; off >>= 1) d += __shfl_down(d, off, 64);
    if (lane == 0) ld[w] = d;
    __syncthreads();
    if (t == 0) T[blockIdx.x] = ld[0] + ld[1] + ld[2] + ld[3];
}

// ---------------------------------------------------------------------------
// Weight prep: z=0,1 cast Wq,Wk -> bf16 (same layout); z=2 transpose Wv.
// grid (16,16,3), block 256.
// ---------------------------------------------------------------------------
__global__ __launch_bounds__(256) void wprep_kernel(
    const float* __restrict__ Wq, const float* __restrict__ Wk,
    const float* __restrict__ Wv,
    ushort_t* __restrict__ Wqb, ushort_t* __restrict__ Wkb,
    ushort_t* __restrict__ WvT)
{
    const int z = blockIdx.z;
    if (z < 2) {
        const float* W = z ? Wk : Wq;
        ushort_t* T = z ? Wkb : Wqb;
        size_t idx = ((size_t)(blockIdx.y * 16 + blockIdx.x)) * 1024 + threadIdx.x * 4;
        float4 f = *(const float4*)(W + idx);
        uint2 u;
        u.x = pk2(f.x, f.y);
        u.y = pk2(f.z, f.w);
        *(uint2*)(T + idx) = u;
        return;
    }
    __shared__ float tile[32][33];
    int tx = threadIdx.x & 31, ty = threadIdx.x >> 5;
    int r0 = blockIdx.y * 32, c0 = blockIdx.x * 32;
#pragma unroll
    for (int p = 0; p < 4; ++p)
        tile[ty + p * 8][tx] = Wv[(size_t)(r0 + ty + p * 8) * 512 + c0 + tx];
    __syncthreads();
#pragma unroll
    for (int p = 0; p < 4; ++p)
        WvT[(size_t)(c0 + ty + p * 8) * 512 + r0 + tx] = f2b(tile[tx][ty + p * 8]);
}

// ---------------------------------------------------------------------------
// colrecip[t] = 1/colsum[t] (+bf16 copy).  16384 elems, grid 64, block 256.
// ---------------------------------------------------------------------------
__global__ __launch_bounds__(256) void colrecip_kernel(
    const float* __restrict__ cs, float* __restrict__ cr,
    ushort_t* __restrict__ crs)
{
    int t = blockIdx.x * 256 + threadIdx.x;
    float r = 1.0f / cs[t];
    cr[t] = r;
    crs[t] = f2b(r);
}

// ---------------------------------------------------------------------------
// NT bf16 MFMA GEMM: C[m,n] = sum_k A[m,k]*B[n,k], k-major bf16, m97-style
// staging (BK=64, global_load_lds 16B, XOR chunk swizzle, conflict-free).
// 128x128 tile, 4 waves, 4x4 MFMA 16x16x32 each.
// MFMA operands SWAPPED vs the m97 baseline (mfma(bf, af)): lane regs r=0..3
// hold 4 CONSECUTIVE output columns j of one row i = ti*16+fm.  This mapping
// is derivable from the baseline kernel's verified mapping for arbitrary
// hidden fragment layouts (operand input layouts are symmetric).
// MODE 0: plain bf16 store (pk2, 8B)               (M = Wq Wk^T;  KM = cln M^T)
// MODE 1: exp(scale*(acc+t1+t2+cc)) bf16 (pk2) + colsum via shfl+LDS  (edots)
// MODE 2: fp32 float4 store * 1/(rowsum+eps); rowsum via MFMA side-column
//         (all 4 regs identical after swap -> 4 divides)             (out)
// MODE 3: (acc + bias[row]) * crcol[col], pk2 bf16 store             (vTs)
// ---------------------------------------------------------------------------
template <int MODE>
__global__ __launch_bounds__(256) void mfma_gemm_kernel(
    const ushort_t* __restrict__ A, const ushort_t* __restrict__ B,
    void* __restrict__ Cout,
    const float* __restrict__ bias,     // MODE3: row bias (bv)
    const float* __restrict__ t1,       // MODE1: row term
    const float* __restrict__ t2,       // MODE1: col term
    const float* __restrict__ cc,       // MODE1: scalar term
    float* __restrict__ colsum,         // MODE1
    const float* __restrict__ crcol,    // MODE3: f32 colrecip
    const ushort_t* __restrict__ crs,   // MODE2: bf16 colrecip
    int K, int N, size_t strideA, size_t strideB, size_t strideC,
    float scale)
{
    __shared__ __align__(16) ushort_t As[128 * 64];   // 16 KB
    __shared__ __align__(16) ushort_t Bs[128 * 64];   // 16 KB
    __shared__ __align__(16) ushort_t crs_lds[(MODE == 2) ? 2048 : 8];
    const int tid = threadIdx.x;
    const ushort_t* Ab = A + strideA * blockIdx.z;
    const ushort_t* Bb = B + strideB * blockIdx.z;
    const int m0 = blockIdx.y * 128;
    const int n0 = blockIdx.x * 128;
    const int wave = tid >> 6;
    const int lane = tid & 63;
    const int fm = lane & 15;
    const int fq = lane >> 4;
    const int fq4 = fq * 4;
    const int fm7 = fm & 7;
    const int wm = (wave >> 1) * 64;
    const int wn = (wave & 1) * 64;

    const int lrow = lane >> 3;            // 0..7
    const int lchunk = lane & 7;           // 0..7
    const int scs = lchunk ^ lrow;         // swizzled source chunk

    const ushort_t* aSrc[4]; const ushort_t* bSrc[4];
    ushort_t* aDst[4]; ushort_t* bDst[4];
#pragma unroll
    for (int p = 0; p < 4; ++p) {
        int row = wave * 32 + p * 8 + lrow;
        aSrc[p] = Ab + (size_t)(m0 + row) * K + scs * 8;
        bSrc[p] = Bb + (size_t)(n0 + row) * K + scs * 8;
        aDst[p] = As + (wave * 32 + p * 8) * 64 + lane * 8;
        bDst[p] = Bs + (wave * 32 + p * 8) * 64 + lane * 8;
    }

    if (MODE == 2) {
        uint4 c4 = *(const uint4*)(crs + (size_t)blockIdx.z * 2048 + tid * 8);
        *(uint4*)&crs_lds[tid * 8] = c4;
    }

    const int cBase = fq ^ fm7;
    const ushort_t* aFrag[4]; const ushort_t* bFrag[4];
#pragma unroll
    for (int t = 0; t < 4; ++t) {
        aFrag[t] = As + (wm + t * 16 + fm) * 64;
        bFrag[t] = Bs + (wn + t * 16 + fm) * 64;
    }

    f32x4 acc[4][4];
    f32x4 sacc[4];
#pragma unroll
    for (int i = 0; i < 4; ++i) {
        sacc[i] = (f32x4){0.f, 0.f, 0.f, 0.f};
#pragma unroll
        for (int j = 0; j < 4; ++j) acc[i][j] = (f32x4){0.f, 0.f, 0.f, 0.f};
    }

    for (int k0 = 0; k0 < K; k0 += 64) {
        __syncthreads();
#pragma unroll
        for (int p = 0; p < 4; ++p) {
            gload16(aSrc[p] + k0, aDst[p]);
            gload16(bSrc[p] + k0, bDst[p]);
        }
        __syncthreads();
#pragma unroll
        for (int s = 0; s < 2; ++s) {
            const int off = ((cBase ^ (s << 2)) << 3);
            bhalf8 af[4], bf[4];
#pragma unroll
            for (int t = 0; t < 4; ++t) {
                af[t] = *(const bhalf8*)(aFrag[t] + off);
                bf[t] = *(const bhalf8*)(bFrag[t] + off);
            }
#pragma unroll
            for (int i = 0; i < 4; ++i)
#pragma unroll
                for (int j = 0; j < 4; ++j)
                    acc[i][j] = __builtin_amdgcn_mfma_f32_16x16x32_bf16(
                        bf[j], af[i], acc[i][j], 0, 0, 0);
            if (MODE == 2) {
                bhalf8 bc = *(const bhalf8*)&crs_lds[k0 + (s << 5) + (fq << 3)];
#pragma unroll
                for (int i = 0; i < 4; ++i)
                    sacc[i] = __builtin_amdgcn_mfma_f32_16x16x32_bf16(
                        bc, af[i], sacc[i], 0, 0, 0);
            }
        }
    }

    // After the swap: acc[ti][tj][r] = C[i][j] with
    //   i = m0 + wm + ti*16 + fm        (one row per lane)
    //   j = n0 + wn + tj*16 + fq*4 + r  (4 consecutive cols per lane)
    if (MODE == 2) {
        float* C = (float*)Cout + strideC * blockIdx.z;
#pragma unroll
        for (int ti = 0; ti < 4; ++ti) {
            const int row = m0 + wm + ti * 16 + fm;
            const float rs = 1.0f / (sacc[ti][0] + 2.049e-5f);
            float* Cr = C + (size_t)row * N + n0 + wn + fq4;
#pragma unroll
            for (int tj = 0; tj < 4; ++tj) {
                f32x4 v;
#pragma unroll
                for (int r = 0; r < 4; ++r) v[r] = acc[ti][tj][r] * rs;
                *(f32x4*)(Cr + tj * 16) = v;
            }
        }
    } else if (MODE == 1) {
        ushort_t* C = (ushort_t*)Cout + strideC * blockIdx.z;
        const float cv = cc[0];
        f32x4 t2c[4];
#pragma unroll
        for (int tj = 0; tj < 4; ++tj) {
            float4 tv = *(const float4*)(t2 + (size_t)blockIdx.z * 2048 +
                                         n0 + wn + tj * 16 + fq4);
            t2c[tj][0] = tv.x + cv;
            t2c[tj][1] = tv.y + cv;
            t2c[tj][2] = tv.z + cv;
            t2c[tj][3] = tv.w + cv;
        }
        float psum[4][4];
#pragma unroll
        for (int tj = 0; tj < 4; ++tj)
#pragma unroll
            for (int r = 0; r < 4; ++r) psum[tj][r] = 0.f;
#pragma unroll
        for (int ti = 0; ti < 4; ++ti) {
            const int row = m0 + wm + ti * 16 + fm;
            const float t1v = t1[(size_t)blockIdx.z * 2048 + row];
            ushort_t* Cr = C + (size_t)row * N + n0 + wn + fq4;
#pragma unroll
            for (int tj = 0; tj < 4; ++tj) {
                ushort_t h0 = f2b(__expf((acc[ti][tj][0] + t1v + t2c[tj][0]) * scale));
                ushort_t h1 = f2b(__expf((acc[ti][tj][1] + t1v + t2c[tj][1]) * scale));
                ushort_t h2 = f2b(__expf((acc[ti][tj][2] + t1v + t2c[tj][2]) * scale));
                ushort_t h3 = f2b(__expf((acc[ti][tj][3] + t1v + t2c[tj][3]) * scale));
                uint2 u;
                u.x = (unsigned)h0 | ((unsigned)h1 << 16);
                u.y = (unsigned)h2 | ((unsigned)h3 << 16);
                *(uint2*)(Cr + tj * 16) = u;
                // sum the quantized values (consistent with stored edots)
                psum[tj][0] += b2f(h0);
                psum[tj][1] += b2f(h1);
                psum[tj][2] += b2f(h2);
                psum[tj][3] += b2f(h3);
            }
        }
        // reduce over i within wave: i varies over fm = lane bits 0..3
#pragma unroll
        for (int tj = 0; tj < 4; ++tj)
#pragma unroll
            for (int r = 0; r < 4; ++r) {
                float v = psum[tj][r];
                v += __shfl_xor(v, 1, 64);
                v += __shfl_xor(v, 2, 64);
                v += __shfl_xor(v, 4, 64);
                v += __shfl_xor(v, 8, 64);
                psum[tj][r] = v;
            }
        float* colpart = (float*)&As[0];
        __syncthreads();
        if (tid < 128) colpart[tid] = 0.f;
        __syncthreads();
        if (fm == 0) {
#pragma unroll
            for (int tj = 0; tj < 4; ++tj)
#pragma unroll
                for (int r = 0; r < 4; ++r)
                    atomicAdd(&colpart[wn + tj * 16 + fq4 + r], psum[tj][r]);
        }
        __syncthreads();
        if (tid < 128)
            atomicAdd(&colsum[(size_t)blockIdx.z * 2048 + n0 + tid], colpart[tid]);
    } else if (MODE == 3) {
        ushort_t* C = (ushort_t*)Cout + strideC * blockIdx.z;
        f32x4 crv[4];
#pragma unroll
        for (int tj = 0; tj < 4; ++tj) {
            float4 cq = *(const float4*)(crcol + (size_t)blockIdx.z * 2048 +
                                         n0 + wn + tj * 16 + fq4);
            crv[tj][0] = cq.x; crv[tj][1] = cq.y;
            crv[tj][2] = cq.z; crv[tj][3] = cq.w;
        }
#pragma unroll
        for (int ti = 0; ti < 4; ++ti) {
            const int row = m0 + wm + ti * 16 + fm;
            const float bvv = bias[row];
            ushort_t* Cr = C + (size_t)row * N + n0 + wn + fq4;
#pragma unroll
            for (int tj = 0; tj < 4; ++tj) {
                uint2 u;
                u.x = pk2((acc[ti][tj][0] + bvv) * crv[tj][0],
                          (acc[ti][tj][1] + bvv) * crv[tj][1]);
                u.y = pk2((acc[ti][tj][2] + bvv) * crv[tj][2],
                          (acc[ti][tj][3] + bvv) * crv[tj][3]);
                *(uint2*)(Cr + tj * 16) = u;
            }
        }
    } else {
        ushort_t* C = (ushort_t*)Cout + strideC * blockIdx.z;
#pragma unroll
        for (int ti = 0; ti < 4; ++ti) {
            const int row = m0 + wm + ti * 16 + fm;
            ushort_t* Cr = C + (size_t)row * N + n0 + wn + fq4;
#pragma unroll
            for (int tj = 0; tj < 4; ++tj) {
                uint2 u;
                u.x = pk2(acc[ti][tj][0], acc[ti][tj][1]);
                u.y = pk2(acc[ti][tj][2], acc[ti][tj][3]);
                *(uint2*)(Cr + tj * 16) = u;
            }
        }
    }
}

// ---------------------------------------------------------------------------
extern "C" void kernel_launch(void* const* d_in, const int* in_sizes, int n_in,
                              void* d_out, int out_size, void* d_ws, size_t ws_size,
                              hipStream_t stream)
{
    const float* inputs  = (const float*)d_in[0];
    const float* context = (const float*)d_in[1];
    const float* g_in    = (const float*)d_in[2];
    const float* b_in    = (const float*)d_in[3];
    const float* g_ctx   = (const float*)d_in[4];
    const float* b_ctx   = (const float*)d_in[5];
    const float* Wq      = (const float*)d_in[6];
    const float* bq      = (const float*)d_in[7];
    const float* Wk      = (const float*)d_in[8];
    const float* bk      = (const float*)d_in[9];
    const float* Wv      = (const float*)d_in[10];
    const float* bv      = (const float*)d_in[11];
    float* out = (float*)d_out;                      // [8,2048,512] fp32

    const size_t QKV  = 8ull * 2048 * 512;           // 8,388,608
    const size_t WSZ  = 512ull * 512;                // 262,144
    const size_t DOTS = 8ull * 2048 * 2048;          // 33,554,432

    ushort_t* xln   = (ushort_t*)d_ws;
    ushort_t* cln   = xln + QKV;
    ushort_t* Wqb   = cln + QKV;
    ushort_t* Wkb   = Wqb + WSZ;
    ushort_t* WvT   = Wkb + WSZ;
    ushort_t* Mb    = WvT + WSZ;                     // Wq Wk^T, bf16 [512][512]
    ushort_t* KM    = Mb + WSZ;                      // cln M^T [16384][512]
    ushort_t* vTs   = KM + QKV;                      // (cln Wv + bv)^T * cr
    ushort_t* edots = vTs + QKV;
    ushort_t* crs   = edots + DOTS;                  // bf16 colrecip [16384]
    float* fbase    = (float*)(crs + 16384);
    float* colsum   = fbase;                         // 16384
    float* colrecip = colsum + 16384;                // 16384
    float* t1       = colrecip + 16384;              // 16384
    float* t2       = t1 + 16384;                    // 16384
    float* wqbk     = t2 + 16384;                    // 512
    float* wkbq     = wqbk + 512;                    // 512
    float* cc       = wkbq + 512;                    // 1
    size_t need_bytes = (4 * QKV + 4 * WSZ + DOTS + 16384) * 2
                      + (4 * 16384 + 1024 + 1) * 4;
    if (ws_size < need_bytes) return;  // fail loudly via validation mismatch

    hipMemsetAsync(colsum, 0, 16384 * sizeof(float), stream);

    mv_bias_kernel<<<dim3(32, 3), 256, 0, stream>>>(Wq, Wk, bq, bk, wqbk, wkbq, cc);

    ln_apply_kernel<<<dim3(16384, 2), 256, 0, stream>>>(
        inputs, context, g_in, b_in, g_ctx, b_ctx, wqbk, wkbq, xln, cln, t1, t2);

    wprep_kernel<<<dim3(16, 16, 3), 256, 0, stream>>>(Wq, Wk, Wv, Wqb, Wkb, WvT);

    // M = Wq @ Wk^T   [512,512]
    mfma_gemm_kernel<0><<<dim3(4, 4, 1), 256, 0, stream>>>(
        Wqb, Wkb, Mb, nullptr, nullptr, nullptr, nullptr, nullptr, nullptr, nullptr,
        512, 512, 0, 0, 0, 1.f);

    // KM[j][a] = sum_b cln[j,b] M[a,b]   [16384,512]
    mfma_gemm_kernel<0><<<dim3(4, 128, 1), 256, 0, stream>>>(
        cln, Mb, KM, nullptr, nullptr, nullptr, nullptr, nullptr, nullptr, nullptr,
        512, 512, 0, 0, 0, 1.f);

    // edots = exp(scale*(xln KM^T + t1 + t2 + cc)), column sums -> colsum
    mfma_gemm_kernel<1><<<dim3(16, 16, 8), 256, 0, stream>>>(
        xln, KM, edots, nullptr, t1, t2, cc, colsum, nullptr, nullptr,
        512, 2048, (size_t)2048 * 512, (size_t)2048 * 512, (size_t)2048 * 2048,
        SCALE_QK);

    colrecip_kernel<<<64, 256, 0, stream>>>(colsum, colrecip, crs);

    // vTs[b,d,j] = (sum_b' WvT[d,b'] cln[j,b'] + bv[d]) * colrecip[b,j]
    mfma_gemm_kernel<3><<<dim3(16, 4, 8), 256, 0, stream>>>(
        WvT, cln, vTs, bv, nullptr, nullptr, nullptr, nullptr, colrecip, nullptr,
        512, 2048, 0, (size_t)2048 * 512, (size_t)512 * 2048, 1.f);

    // out = diag(1/(E cr + eps)) * E @ vTs^T   (rowsum via MFMA side-column)
    mfma_gemm_kernel<2><<<dim3(4, 16, 8), 256, 0, stream>>>(
        edots, vTs, out, nullptr, nullptr, nullptr, nullptr, nullptr, nullptr, crs,
        2048, 512, (size_t)2048 * 2048, (size_t)512 * 2048, (size_t)2048 * 512,
        1.f);
}